// Round 4
// baseline (550.453 us; speedup 1.0000x reference)
//
#include <hip/hip_runtime.h>
#include <math.h>

#define NN 4096
#define EE 131072
#define IN_DIM 512
#define HID 256
#define OUT_DIM 64
#define ECAP 128

typedef __attribute__((ext_vector_type(8))) short bf8_t;
typedef __attribute__((ext_vector_type(4))) float f4_t;
typedef __attribute__((ext_vector_type(8))) unsigned short us8_t;

// ---------------- bf16 helpers (RNE) ----------------
__device__ __forceinline__ unsigned short f2bf(float v){
  union { float f; unsigned u; } x; x.f = v;
  unsigned r = x.u + 0x7fffu + ((x.u >> 16) & 1u);
  return (unsigned short)(r >> 16);
}
__device__ __forceinline__ float bf2f(unsigned short h){
  union { float f; unsigned u; } x; x.u = ((unsigned)h) << 16;
  return x.f;
}

__device__ __forceinline__ float waveReduceSum(float v){
#pragma unroll
  for (int off = 32; off > 0; off >>= 1) v += __shfl_down(v, off);
  return v;
}

// ---------------- graph build: bitmask + ELL ----------------
__global__ void k_build_bits(const int* __restrict__ ei, unsigned* __restrict__ bits){
  int e = blockIdx.x * blockDim.x + threadIdx.x;
  if (e < EE){
    int r = ei[e], c = ei[EE + e];
    atomicOr(&bits[r * 128 + (c >> 5)], 1u << (c & 31));
  }
}

__global__ __launch_bounds__(128) void k_ell(const unsigned* __restrict__ bits,
                                             int* __restrict__ ell, int* __restrict__ cnt,
                                             float* __restrict__ dinv){
  int r = blockIdx.x, t = threadIdx.x;
  unsigned w = bits[r * 128 + t];
  int c = __popc(w);
  __shared__ int sc[128];
  sc[t] = c; __syncthreads();
  for (int off = 1; off < 128; off <<= 1){
    int a = sc[t], b = (t >= off) ? sc[t - off] : 0;
    __syncthreads(); sc[t] = a + b; __syncthreads();
  }
  int total = sc[127];
  int pos = sc[t] - c;
  int base = r * ECAP;
  while (w){
    int b = __ffs(w) - 1; w &= w - 1;
    if (pos < ECAP) ell[base + pos] = t * 32 + b;
    pos++;
  }
  if (t == 0){
    cnt[r] = (total < ECAP) ? total : ECAP;
    dinv[r] = 1.0f / sqrtf((float)total + 2.0f);
  }
}

// ---------------- fused SpMM (ELL, values==1) + GCN epilogue (+ optional score) ----------------
template<int NCOLS, int RELU, int SC>
__global__ __launch_bounds__(256) void k_spmm_ell(
    const int* __restrict__ ell, const int* __restrict__ cnt,
    const float* __restrict__ Zs, const float* __restrict__ dinv,
    const float* __restrict__ bias, float* __restrict__ out,
    const float* __restrict__ scw, float* __restrict__ score)
{
  int r = blockIdx.x;
  __shared__ int s_idx[ECAP];
  __shared__ int s_n;
  __shared__ float sh[4 * NCOLS];
  __shared__ float sd[4], sq[4];
  if (threadIdx.x == 0) s_n = cnt[r];
  for (int i = threadIdx.x; i < ECAP; i += 256) s_idx[i] = ell[r * ECAP + i];
  __syncthreads();
  int n = s_n; if (n > ECAP) n = ECAP;
  int wv = threadIdx.x >> 6, lane = threadIdx.x & 63;
  if (NCOLS == 256){
    f4_t acc = (f4_t){0.f, 0.f, 0.f, 0.f};
    for (int e = wv; e < n; e += 4){
      const f4_t* row = (const f4_t*)(Zs + (size_t)s_idx[e] * 256);
      acc += row[lane];
    }
    ((f4_t*)(sh + wv * 256))[lane] = acc;
  } else {
    float acc = 0.f;
    for (int e = wv; e < n; e += 4)
      acc += Zs[(size_t)s_idx[e] * 64 + lane];
    sh[wv * 64 + lane] = acc;
  }
  __syncthreads();
  int t = threadIdx.x;
  float o = 0.f;
  if (t < NCOLS){
    float y = sh[t] + sh[NCOLS + t] + sh[2 * NCOLS + t] + sh[3 * NCOLS + t];
    float z = Zs[(size_t)r * NCOLS + t];
    o = dinv[r] * (y + 2.0f * z) + bias[t];
    if (RELU) o = fmaxf(o, 0.f);
    out[(size_t)r * NCOLS + t] = o;
  }
  if (SC){
    float w = scw[t];
    float d = waveReduceSum(o * w);
    float q = waveReduceSum(w * w);
    if (!lane){ sd[wv] = d; sq[wv] = q; }
    __syncthreads();
    if (!t) score[r] = tanhf((sd[0] + sd[1] + sd[2] + sd[3]) / sqrtf(sq[0] + sq[1] + sq[2] + sq[3]));
  }
}

// ---------------- pool-1 squaring (u8 Rb) ----------------
// Rb[k][s] = (A0+I)[k][perm1[s]] as u8
__global__ __launch_bounds__(256) void k_build_Rb(const int* __restrict__ ell, const int* __restrict__ cnt,
                                                  const int* __restrict__ invsel,
                                                  unsigned char* __restrict__ Rb){
  int k = blockIdx.x;
  __shared__ unsigned char row[2048];
  for (int i = threadIdx.x; i < 512; i += 256) ((int*)row)[i] = 0;
  __syncthreads();
  int n = cnt[k];
  for (int e = threadIdx.x; e < n; e += 256){
    int s = invsel[ell[k * ECAP + e]];
    if (s >= 0) row[s] = 1;
  }
  __syncthreads();
  if (threadIdx.x == 0){
    int sk = invsel[k];
    if (sk >= 0) row[sk] += 1;
  }
  __syncthreads();
  *(uint2*)(Rb + (size_t)k * 2048 + threadIdx.x * 8) = *(uint2*)(row + threadIdx.x * 8);
}

// A1h[r][:] = Rb[pr][:] + sum_{k in ell[pr]} Rb[k][:]; diag (col==r) zeroed; dinv1 fused.
// Byte values <=130 -> carry-free packed 32-bit adds; exact in bf16.
__global__ __launch_bounds__(256) void k_sq1(const int* __restrict__ ell, const int* __restrict__ cnt,
                                             const int* __restrict__ perm,
                                             const unsigned char* __restrict__ Rb,
                                             unsigned short* __restrict__ A1h,
                                             float* __restrict__ dinv1){
  int r = blockIdx.x;
  int pr = perm[r];
  __shared__ int s_idx[ECAP];
  __shared__ int s_n;
  __shared__ float sred[4];
  if (threadIdx.x == 0) s_n = cnt[pr];
  for (int i = threadIdx.x; i < ECAP; i += 256) s_idx[i] = ell[pr * ECAP + i];
  __syncthreads();
  int n = s_n; if (n > ECAP) n = ECAP;
  int colb = threadIdx.x * 8;
  uint2 acc = *(const uint2*)(Rb + (size_t)pr * 2048 + colb);
  for (int e = 0; e < n; ++e){
    uint2 v = *(const uint2*)(Rb + (size_t)s_idx[e] * 2048 + colb);
    acc.x += v.x; acc.y += v.y;   // bytewise, no carries (values <=130)
  }
  float fs = 0.f;
  us8_t o;
#pragma unroll
  for (int j = 0; j < 8; ++j){
    unsigned byte = ((j < 4 ? acc.x : acc.y) >> (8 * (j & 3))) & 0xFFu;
    if (colb + j == r) byte = 0;
    float f = (float)byte;
    fs += f;
    o[j] = f2bf(f);
  }
  *(us8_t*)(A1h + (size_t)r * 2048 + colb) = o;
  fs = waveReduceSum(fs);
  int lane = threadIdx.x & 63, wd = threadIdx.x >> 6;
  if (!lane) sred[wd] = fs;
  __syncthreads();
  if (!threadIdx.x)
    dinv1[r] = 1.0f / sqrtf(sred[0] + sred[1] + sred[2] + sred[3] + 2.0f);
}

// ---------------- bf16 transpose (h [+l]) ----------------
template<int TWO>
__global__ __launch_bounds__(256) void k_tr_b(const unsigned short* __restrict__ Sh,
                                              const unsigned short* __restrict__ Sl,
                                              unsigned short* __restrict__ Dh,
                                              unsigned short* __restrict__ Dl, int R, int C){
  __shared__ unsigned short th[32][33];
  __shared__ unsigned short tl[TWO ? 32 : 1][TWO ? 33 : 1];
  int bx = blockIdx.x * 32, by = blockIdx.y * 32;
  int tx = threadIdx.x & 31, ty = threadIdx.x >> 5;
#pragma unroll
  for (int i = 0; i < 4; ++i){
    th[ty + i * 8][tx] = Sh[(size_t)(by + ty + i * 8) * C + bx + tx];
    if (TWO) tl[ty + i * 8][tx] = Sl[(size_t)(by + ty + i * 8) * C + bx + tx];
  }
  __syncthreads();
#pragma unroll
  for (int i = 0; i < 4; ++i){
    size_t o = (size_t)(bx + ty + i * 8) * R + by + tx;
    Dh[o] = th[tx][ty + i * 8];
    if (TWO) Dl[o] = tl[tx][ty + i * 8];
  }
}

template<int SRCL>
__global__ void k_dinv_bf(const unsigned short* __restrict__ Ah,
                          const unsigned short* __restrict__ Al,
                          float* __restrict__ dinv, int n){
  int row = blockIdx.x;
  float s = 0.f;
  for (int j = threadIdx.x; j < n; j += 256){
    float v = bf2f(Ah[(size_t)row * n + j]);
    if (SRCL) v += bf2f(Al[(size_t)row * n + j]);
    s += v;
  }
  s = waveReduceSum(s);
  __shared__ float sh[4];
  int lane = threadIdx.x & 63, wid = threadIdx.x >> 6;
  if (lane == 0) sh[wid] = s;
  __syncthreads();
  if (threadIdx.x == 0){
    float d = sh[0] + sh[1] + sh[2] + sh[3] + 2.0f;
    dinv[row] = (d > 0.f) ? (1.0f / sqrtf(d)) : 0.0f;
  }
}

// ---------------- pipelined MFMA GEMM ----------------
// C(MxN) = (Ah[+Al]) @ (Bh[+Bl]); A row-major [M][K] bf16, B as Bt [N][K] bf16.
// EPI 1: split acc -> Ch,Cl (flag!=0: zero diagonal first)
// EPI 2: Cf = dinv[row]*acc
// EPI 3: Cf = act(dinv[row]*(acc + 2*Zs) + bias), flag = relu
// EPI 4: sv = dinv[row]*acc; Cf = sv (row-major); Ch/Cl = split(sv) TRANSPOSED [col][row]
template<int HAS_AL, int HAS_BL, int HAS_LL, int EPI>
__global__ __launch_bounds__(256) void k_mm(
    const unsigned short* __restrict__ Ah, const unsigned short* __restrict__ Al,
    const unsigned short* __restrict__ Bh, const unsigned short* __restrict__ Bl,
    int M, int N, int K,
    float* __restrict__ Cf, unsigned short* __restrict__ Ch, unsigned short* __restrict__ Cl,
    const float* __restrict__ dinv, const float* __restrict__ Zs,
    const float* __restrict__ bias, int flag)
{
  constexpr int NARR = 2 + HAS_AL + HAS_BL;
  __shared__ char lds[NARR * 8192];
  char* LAH = lds;
  char* LBH = lds + 8192;
  char* LAL = lds + 16384;                 // valid iff HAS_AL
  char* LBL = lds + (2 + HAS_AL) * 8192;   // valid iff HAS_BL

  const int tid = threadIdx.x, lane = tid & 63, wid = tid >> 6;
  const int wm = wid >> 1, wn = wid & 1;
  const int bm = blockIdx.y << 6, bn = blockIdx.x << 6;
  const int l15 = lane & 15, l4 = lane >> 4;

  f4_t acc[2][2];
#pragma unroll
  for (int i = 0; i < 2; ++i)
#pragma unroll
    for (int j = 0; j < 2; ++j) acc[i][j] = (f4_t){0.f, 0.f, 0.f, 0.f};

  const size_t rb = (size_t)K * 2;
  const char* pAh = (const char*)Ah + (size_t)bm * rb;
  const char* pAl = HAS_AL ? (const char*)Al + (size_t)bm * rb : nullptr;
  const char* pBh = (const char*)Bh + (size_t)bn * rb;
  const char* pBl = HAS_BL ? (const char*)Bl + (size_t)bn * rb : nullptr;

  int4 rg[2][NARR];

  auto issue = [&](int t){
    const size_t kb = (size_t)t * 128;
#pragma unroll
    for (int it = 0; it < 2; ++it){
      const int c = tid + (it << 8);
      const int row = c >> 3, kc = (c & 7) << 4;
      const size_t go = (size_t)row * rb + kb + kc;
      rg[it][0] = *(const int4*)(pAh + go);
      rg[it][1] = *(const int4*)(pBh + go);
      if (HAS_AL) rg[it][2] = *(const int4*)(pAl + go);
      if (HAS_BL) rg[it][2 + HAS_AL] = *(const int4*)(pBl + go);
    }
  };
  auto commit = [&](){
#pragma unroll
    for (int it = 0; it < 2; ++it){
      const int c = tid + (it << 8);
      const int row = c >> 3, kc = (c & 7) << 4;
      const int off = row * 128 + (kc ^ ((row & 7) << 4));
      *(int4*)(LAH + off) = rg[it][0];
      *(int4*)(LBH + off) = rg[it][1];
      if (HAS_AL) *(int4*)(LAL + off) = rg[it][2];
      if (HAS_BL) *(int4*)(LBL + off) = rg[it][2 + HAS_AL];
    }
  };

  const int T = K >> 6;
  issue(0);
  for (int t = 0; t < T; ++t){
    __syncthreads();
    commit();
    __syncthreads();
    if (t + 1 < T) issue(t + 1);   // prefetch next tile; latency hides under MFMAs
#pragma unroll
    for (int ks = 0; ks < 2; ++ks){
      bf8_t aH[2], aL[2], bH[2], bL[2];
#pragma unroll
      for (int f = 0; f < 2; ++f){
        int ar = wm * 32 + f * 16 + l15;
        int ao = ar * 128 + (((ks * 64) + (l4 << 4)) ^ ((ar & 7) << 4));
        aH[f] = *(const bf8_t*)(LAH + ao);
        if (HAS_AL) aL[f] = *(const bf8_t*)(LAL + ao);
        int br = wn * 32 + f * 16 + l15;
        int bo = br * 128 + (((ks * 64) + (l4 << 4)) ^ ((br & 7) << 4));
        bH[f] = *(const bf8_t*)(LBH + bo);
        if (HAS_BL) bL[f] = *(const bf8_t*)(LBL + bo);
      }
#pragma unroll
      for (int i = 0; i < 2; ++i)
#pragma unroll
        for (int j = 0; j < 2; ++j){
          acc[i][j] = __builtin_amdgcn_mfma_f32_16x16x32_bf16(aH[i], bH[j], acc[i][j], 0, 0, 0);
          if (HAS_BL) acc[i][j] = __builtin_amdgcn_mfma_f32_16x16x32_bf16(aH[i], bL[j], acc[i][j], 0, 0, 0);
          if (HAS_AL) acc[i][j] = __builtin_amdgcn_mfma_f32_16x16x32_bf16(aL[i], bH[j], acc[i][j], 0, 0, 0);
          if (HAS_LL) acc[i][j] = __builtin_amdgcn_mfma_f32_16x16x32_bf16(aL[i], bL[j], acc[i][j], 0, 0, 0);
        }
    }
  }

#pragma unroll
  for (int i = 0; i < 2; ++i)
#pragma unroll
    for (int j = 0; j < 2; ++j)
#pragma unroll
      for (int r = 0; r < 4; ++r){
        int grow = bm + wm * 32 + i * 16 + l4 * 4 + r;
        int gcol = bn + wn * 32 + j * 16 + l15;
        float v = acc[i][j][r];
        size_t o = (size_t)grow * N + gcol;
        if (EPI == 1){
          if (flag && grow == gcol) v = 0.f;
          unsigned short h = f2bf(v);
          Ch[o] = h; Cl[o] = f2bf(v - bf2f(h));
        } else if (EPI == 2){
          Cf[o] = dinv[grow] * v;
        } else if (EPI == 3){
          float out = dinv[grow] * (v + 2.0f * Zs[o]) + bias[gcol];
          if (flag) out = fmaxf(out, 0.f);
          Cf[o] = out;
        } else { // EPI == 4
          float sv = dinv[grow] * v;
          Cf[o] = sv;
          unsigned short h = f2bf(sv);
          size_t ot = (size_t)gcol * M + grow;
          Ch[ot] = h; Cl[ot] = f2bf(sv - bf2f(h));
        }
      }
}

// ---------------- elementwise helpers ----------------
__global__ void k_split(const float* __restrict__ X, unsigned short* __restrict__ H,
                        unsigned short* __restrict__ L, int n){
  int i = blockIdx.x * 256 + threadIdx.x;
  if (i < n){
    float v = X[i];
    unsigned short h = f2bf(v);
    H[i] = h; L[i] = f2bf(v - bf2f(h));
  }
}

__global__ __launch_bounds__(256) void k_tsplit(const float* __restrict__ X, int R, int C,
                                                unsigned short* __restrict__ Th,
                                                unsigned short* __restrict__ Tl){
  __shared__ float t[32][33];
  int bx = blockIdx.x * 32, by = blockIdx.y * 32;
  int tx = threadIdx.x & 31, ty = threadIdx.x >> 5;
#pragma unroll
  for (int i = 0; i < 4; ++i)
    t[ty + i * 8][tx] = X[(size_t)(by + ty + i * 8) * C + bx + tx];
  __syncthreads();
#pragma unroll
  for (int i = 0; i < 4; ++i){
    float v = t[tx][ty + i * 8];
    unsigned short h = f2bf(v);
    size_t o = (size_t)(bx + ty + i * 8) * R + by + tx;
    Th[o] = h; Tl[o] = f2bf(v - bf2f(h));
  }
}

// batch-transpose-split the five 256x256 weights in one dispatch
__global__ __launch_bounds__(256) void k_tsplit5(const float* __restrict__ w0, const float* __restrict__ w1,
                                                 const float* __restrict__ w2, const float* __restrict__ w3,
                                                 const float* __restrict__ w4,
                                                 unsigned short* __restrict__ Th, unsigned short* __restrict__ Tl){
  const float* X = (blockIdx.z == 0) ? w0 : (blockIdx.z == 1) ? w1 : (blockIdx.z == 2) ? w2 :
                   (blockIdx.z == 3) ? w3 : w4;
  unsigned short* th = Th + (size_t)blockIdx.z * 65536;
  unsigned short* tl = Tl + (size_t)blockIdx.z * 65536;
  __shared__ float t[32][33];
  int bx = blockIdx.x * 32, by = blockIdx.y * 32;
  int tx = threadIdx.x & 31, ty = threadIdx.x >> 5;
#pragma unroll
  for (int i = 0; i < 4; ++i)
    t[ty + i * 8][tx] = X[(size_t)(by + ty + i * 8) * 256 + bx + tx];
  __syncthreads();
#pragma unroll
  for (int i = 0; i < 4; ++i){
    float v = t[tx][ty + i * 8];
    unsigned short h = f2bf(v);
    size_t o = (size_t)(bx + ty + i * 8) * 256 + by + tx;
    th[o] = h; tl[o] = f2bf(v - bf2f(h));
  }
}

// score[row] = tanh((x.w)/||w||), wnorm computed in-block
__global__ void k_score(const float* __restrict__ x, const float* __restrict__ w,
                        float* __restrict__ score){
  int row = blockIdx.x;
  float wv = w[threadIdx.x];
  float xv = x[(size_t)row * HID + threadIdx.x];
  float d = waveReduceSum(xv * wv);
  float q = waveReduceSum(wv * wv);
  __shared__ float sd[4], sq[4];
  int lane = threadIdx.x & 63, wd = threadIdx.x >> 6;
  if (!lane){ sd[wd] = d; sq[wd] = q; }
  __syncthreads();
  if (!threadIdx.x)
    score[row] = tanhf((sd[0] + sd[1] + sd[2] + sd[3]) / sqrtf(sq[0] + sq[1] + sq[2] + sq[3]));
}

// rank_i = #{j: s_j > s_i} + #{j<i: s_j == s_i}; perm[rank]=i; inv[i]=rank or -1
__global__ void k_topk(const float* __restrict__ score, int n, int k,
                       int* __restrict__ perm, int* __restrict__ inv){
  int i = blockIdx.x; float si = score[i];
  int cnt = 0;
  for (int j = threadIdx.x; j < n; j += 256){
    float sj = score[j];
    if (sj > si || (sj == si && j < i)) cnt++;
  }
#pragma unroll
  for (int off = 32; off > 0; off >>= 1) cnt += __shfl_down(cnt, off);
  __shared__ int sh[4];
  int lane = threadIdx.x & 63, wid = threadIdx.x >> 6;
  if (lane == 0) sh[wid] = cnt;
  __syncthreads();
  if (threadIdx.x == 0){
    int rank = sh[0] + sh[1] + sh[2] + sh[3];
    if (rank < k){ perm[rank] = i; inv[i] = rank; }
    else inv[i] = -1;
  }
}

__global__ void k_pool_x2(const float* __restrict__ x, const float* __restrict__ score,
                          const int* __restrict__ perm,
                          unsigned short* __restrict__ xh, unsigned short* __restrict__ xl, int C){
  int r = blockIdx.x; int pr = perm[r]; float s = score[pr];
  for (int c = threadIdx.x; c < C; c += 256){
    float v = x[(size_t)pr * C + c] * s;
    unsigned short h = f2bf(v);
    xh[(size_t)r * C + c] = h;
    xl[(size_t)r * C + c] = f2bf(v - bf2f(h));
  }
}

// D[r][c] = (Sh+Sl)[perm[r]][c] + (perm[r]==c), resplit
template<int SRCL, int OUTL>
__global__ void k_grow_b(const unsigned short* __restrict__ Sh, const unsigned short* __restrict__ Sl,
                         const int* __restrict__ perm,
                         unsigned short* __restrict__ Dh, unsigned short* __restrict__ Dl, int n){
  int r = blockIdx.x, pr = perm[r];
  for (int c = threadIdx.x; c < n; c += 256){
    float v = bf2f(Sh[(size_t)pr * n + c]);
    if (SRCL) v += bf2f(Sl[(size_t)pr * n + c]);
    if (pr == c) v += 1.f;
    unsigned short h = f2bf(v);
    Dh[(size_t)r * n + c] = h;
    if (OUTL) Dl[(size_t)r * n + c] = f2bf(v - bf2f(h));
  }
}

// fused unpool: v = res[r] + (inv[r]>=0 ? xs[inv[r]] : 0), written as bf16 split
__global__ void k_unpool_split(const float* __restrict__ res, const float* __restrict__ xs,
                               const int* __restrict__ inv,
                               unsigned short* __restrict__ xh, unsigned short* __restrict__ xl){
  int r = blockIdx.x; int ir = inv[r];
  int c = threadIdx.x;
  float v = res[(size_t)r * HID + c];
  if (ir >= 0) v += xs[(size_t)ir * HID + c];
  unsigned short h = f2bf(v);
  xh[(size_t)r * HID + c] = h;
  xl[(size_t)r * HID + c] = f2bf(v - bf2f(h));
}

// ---------------- host orchestration ----------------
extern "C" void kernel_launch(void* const* d_in, const int* in_sizes, int n_in,
                              void* d_out, int out_size, void* d_ws, size_t ws_size,
                              hipStream_t stream){
  (void)in_sizes; (void)n_in; (void)out_size;
  const float* x_in = (const float*)d_in[0];
  const int*   ei   = (const int*)d_in[1];
  const float* dW0 = (const float*)d_in[2];
  const float* dW1 = (const float*)d_in[3];
  const float* dW2 = (const float*)d_in[4];
  const float* dW3 = (const float*)d_in[5];
  const float* db0 = (const float*)d_in[6];
  const float* db1 = (const float*)d_in[7];
  const float* db2 = (const float*)d_in[8];
  const float* db3 = (const float*)d_in[9];
  const float* pw0 = (const float*)d_in[10];
  const float* pw1 = (const float*)d_in[11];
  const float* pw2 = (const float*)d_in[12];
  const float* uW0 = (const float*)d_in[13];
  const float* uW1 = (const float*)d_in[14];
  const float* uW2 = (const float*)d_in[15];
  const float* ub0 = (const float*)d_in[16];
  const float* ub1 = (const float*)d_in[17];
  const float* ub2 = (const float*)d_in[18];

  char* p = (char*)d_ws;
  auto alloc = [&](size_t nbytes) -> void* {
    void* q = (void*)p; p += (nbytes + 255) & ~(size_t)255; return q;
  };
  unsigned* bits = (unsigned*)alloc((size_t)4096 * 128 * 4);
  int* ell = (int*)alloc((size_t)4096 * ECAP * 4);
  int* cnt = (int*)alloc(4096 * 4);
  int* inv1 = (int*)alloc(4096 * 4);
  int* inv2 = (int*)alloc(2048 * 4);
  int* inv3 = (int*)alloc(1024 * 4);
  unsigned char* Rb = (unsigned char*)alloc((size_t)4096 * 2048);
  unsigned short* A1h = (unsigned short*)alloc((size_t)2048 * 2048 * 2);
  unsigned short* A1T = (unsigned short*)alloc((size_t)2048 * 2048 * 2);
  unsigned short* A2h = (unsigned short*)alloc((size_t)1024 * 1024 * 2);
  unsigned short* A2l = (unsigned short*)alloc((size_t)1024 * 1024 * 2);
  unsigned short* A2Th = (unsigned short*)alloc((size_t)1024 * 1024 * 2);
  unsigned short* A2Tl = (unsigned short*)alloc((size_t)1024 * 1024 * 2);
  unsigned short* A3h = (unsigned short*)alloc((size_t)512 * 512 * 2);
  unsigned short* A3l = (unsigned short*)alloc((size_t)512 * 512 * 2);
  unsigned short* Lb2h = (unsigned short*)alloc((size_t)1024 * 2048 * 2);
  unsigned short* Rt2h = (unsigned short*)alloc((size_t)1024 * 2048 * 2);
  unsigned short* Lb3h = (unsigned short*)alloc((size_t)512 * 1024 * 2);
  unsigned short* Lb3l = (unsigned short*)alloc((size_t)512 * 1024 * 2);
  unsigned short* Rt3h = (unsigned short*)alloc((size_t)512 * 1024 * 2);
  unsigned short* Rt3l = (unsigned short*)alloc((size_t)512 * 1024 * 2);
  unsigned short* xinh = (unsigned short*)alloc((size_t)4096 * 512 * 2);
  unsigned short* xinl = (unsigned short*)alloc((size_t)4096 * 512 * 2);
  float* x0 = (float*)alloc((size_t)4096 * HID * 4);
  float* x1 = (float*)alloc((size_t)2048 * HID * 4);
  float* x2 = (float*)alloc((size_t)1024 * HID * 4);
  float* xv = (float*)alloc((size_t)2048 * HID * 4);
  unsigned short* xuh = (unsigned short*)alloc((size_t)4096 * HID * 2);
  unsigned short* xul = (unsigned short*)alloc((size_t)4096 * HID * 2);
  unsigned short* xph = (unsigned short*)alloc((size_t)2048 * HID * 2);
  unsigned short* xpl = (unsigned short*)alloc((size_t)2048 * HID * 2);
  unsigned short* W0th = (unsigned short*)alloc((size_t)256 * 512 * 2);
  unsigned short* W0tl = (unsigned short*)alloc((size_t)256 * 512 * 2);
  unsigned short* W5th = (unsigned short*)alloc((size_t)5 * 256 * 256 * 2);
  unsigned short* W5tl = (unsigned short*)alloc((size_t)5 * 256 * 256 * 2);
  unsigned short* W2th = (unsigned short*)alloc((size_t)64 * 256 * 2);
  unsigned short* W2tl = (unsigned short*)alloc((size_t)64 * 256 * 2);
  float* Zs  = (float*)alloc((size_t)4096 * HID * 4);
  unsigned short* ZsTh = (unsigned short*)alloc((size_t)256 * 2048 * 2);
  unsigned short* ZsTl = (unsigned short*)alloc((size_t)256 * 2048 * 2);
  float* dinv0 = (float*)alloc(4096 * 4);
  float* dinv1 = (float*)alloc(2048 * 4);
  float* dinv2 = (float*)alloc(1024 * 4);
  float* dinv3 = (float*)alloc(512 * 4);
  float* score = (float*)alloc(4096 * 4);
  int* perm1 = (int*)alloc(2048 * 4);
  int* perm2 = (int*)alloc(1024 * 4);
  int* perm3 = (int*)alloc(512 * 4);
  if ((size_t)(p - (char*)d_ws) > ws_size) return;

  // ---- weight prep (3 dispatches) ----
  { dim3 g(8, 16); k_tsplit<<<g, 256, 0, stream>>>(dW0, IN_DIM, HID, W0th, W0tl); }
  { dim3 g(8, 8, 5); k_tsplit5<<<g, 256, 0, stream>>>(dW1, dW2, dW3, uW0, uW1, W5th, W5tl); }
  { dim3 g(2, 8); k_tsplit<<<g, 256, 0, stream>>>(uW2, HID, OUT_DIM, W2th, W2tl); }

  // ---- graph build ----
  hipMemsetAsync(bits, 0, (size_t)4096 * 128 * 4, stream);
  k_build_bits<<<EE / 256, 256, 0, stream>>>(ei, bits);
  k_ell<<<4096, 128, 0, stream>>>(bits, ell, cnt, dinv0);

  // ---- conv0 (+ pool-1 score fused into spmm) ----
  k_split<<<(4096 * 512 + 255) / 256, 256, 0, stream>>>(x_in, xinh, xinl, 4096 * 512);
  { dim3 g(4, 64);
    k_mm<1,1,0,2><<<g, 256, 0, stream>>>(xinh, xinl, W0th, W0tl, 4096, HID, IN_DIM,
                                         Zs, nullptr, nullptr, dinv0, nullptr, nullptr, 0); }
  k_spmm_ell<256,1,1><<<4096, 256, 0, stream>>>(ell, cnt, Zs, dinv0, db0, x0, pw0, score);

  // ---- pool 1 (4096 -> 2048) ----
  k_topk<<<4096, 256, 0, stream>>>(score, 4096, 2048, perm1, inv1);
  k_pool_x2<<<2048, 256, 0, stream>>>(x0, score, perm1, xph, xpl, HID);
  k_build_Rb<<<4096, 256, 0, stream>>>(ell, cnt, inv1, Rb);
  k_sq1<<<2048, 256, 0, stream>>>(ell, cnt, perm1, Rb, A1h, dinv1);
  // conv1
  { dim3 g(4, 32);
    k_mm<1,1,0,4><<<g, 256, 0, stream>>>(xph, xpl, W5th, W5tl, 2048, HID, HID,
                                         Zs, ZsTh, ZsTl, dinv1, nullptr, nullptr, 0); }
  { dim3 g(4, 32);
    k_mm<0,1,0,3><<<g, 256, 0, stream>>>(A1h, nullptr, ZsTh, ZsTl, 2048, HID, 2048,
                                         x1, nullptr, nullptr, dinv1, Zs, db1, 1); }

  // ---- pool 2 (2048 -> 1024) ----
  k_score<<<2048, 256, 0, stream>>>(x1, pw1, score);
  k_topk<<<2048, 256, 0, stream>>>(score, 2048, 1024, perm2, inv2);
  { dim3 g(64, 64); k_tr_b<0><<<g, 256, 0, stream>>>(A1h, nullptr, A1T, nullptr, 2048, 2048); }
  k_grow_b<0,0><<<1024, 256, 0, stream>>>(A1h, nullptr, perm2, Lb2h, nullptr, 2048);
  k_grow_b<0,0><<<1024, 256, 0, stream>>>(A1T, nullptr, perm2, Rt2h, nullptr, 2048);
  { dim3 g(16, 16);
    k_mm<0,0,0,1><<<g, 256, 0, stream>>>(Lb2h, nullptr, Rt2h, nullptr, 1024, 1024, 2048,
                                         nullptr, A2h, A2l, nullptr, nullptr, nullptr, 1); }
  k_dinv_bf<1><<<1024, 256, 0, stream>>>(A2h, A2l, dinv2, 1024);
  k_pool_x2<<<1024, 256, 0, stream>>>(x1, score, perm2, xph, xpl, HID);
  // conv2
  { dim3 g(4, 16);
    k_mm<1,1,0,4><<<g, 256, 0, stream>>>(xph, xpl, W5th + 65536, W5tl + 65536, 1024, HID, HID,
                                         Zs, ZsTh, ZsTl, dinv2, nullptr, nullptr, 0); }
  { dim3 g(4, 16);
    k_mm<1,1,0,3><<<g, 256, 0, stream>>>(A2h, A2l, ZsTh, ZsTl, 1024, HID, 1024,
                                         x2, nullptr, nullptr, dinv2, Zs, db2, 1); }

  // ---- pool 3 (1024 -> 512) ----
  k_score<<<1024, 256, 0, stream>>>(x2, pw2, score);
  k_topk<<<1024, 256, 0, stream>>>(score, 1024, 512, perm3, inv3);
  { dim3 g(32, 32); k_tr_b<1><<<g, 256, 0, stream>>>(A2h, A2l, A2Th, A2Tl, 1024, 1024); }
  k_grow_b<1,1><<<512, 256, 0, stream>>>(A2h, A2l, perm3, Lb3h, Lb3l, 1024);
  k_grow_b<1,1><<<512, 256, 0, stream>>>(A2Th, A2Tl, perm3, Rt3h, Rt3l, 1024);
  { dim3 g(8, 8);
    k_mm<1,1,1,1><<<g, 256, 0, stream>>>(Lb3h, Lb3l, Rt3h, Rt3l, 512, 512, 1024,
                                         nullptr, A3h, A3l, nullptr, nullptr, nullptr, 1); }
  k_dinv_bf<1><<<512, 256, 0, stream>>>(A3h, A3l, dinv3, 512);
  k_pool_x2<<<512, 256, 0, stream>>>(x2, score, perm3, xph, xpl, HID);
  // conv3
  { dim3 g(4, 8);
    k_mm<1,1,0,4><<<g, 256, 0, stream>>>(xph, xpl, W5th + 2 * 65536, W5tl + 2 * 65536, 512, HID, HID,
                                         Zs, ZsTh, ZsTl, dinv3, nullptr, nullptr, 0); }
  { dim3 g(4, 8);
    k_mm<1,1,0,3><<<g, 256, 0, stream>>>(A3h, A3l, ZsTh, ZsTl, 512, HID, 512,
                                         xv, nullptr, nullptr, dinv3, Zs, db3, 1); }   // xv = x3

  // ---- up 0 (res=x2, inv3, A2) ----
  k_unpool_split<<<1024, 256, 0, stream>>>(x2, xv, inv3, xuh, xul);
  { dim3 g(4, 16);
    k_mm<1,1,0,4><<<g, 256, 0, stream>>>(xuh, xul, W5th + 3 * 65536, W5tl + 3 * 65536, 1024, HID, HID,
                                         Zs, ZsTh, ZsTl, dinv2, nullptr, nullptr, 0); }
  { dim3 g(4, 16);
    k_mm<1,1,0,3><<<g, 256, 0, stream>>>(A2h, A2l, ZsTh, ZsTl, 1024, HID, 1024,
                                         xv, nullptr, nullptr, dinv2, Zs, ub0, 1); }

  // ---- up 1 (res=x1, inv2, A1) ----
  k_unpool_split<<<2048, 256, 0, stream>>>(x1, xv, inv2, xuh, xul);
  { dim3 g(4, 32);
    k_mm<1,1,0,4><<<g, 256, 0, stream>>>(xuh, xul, W5th + 4 * 65536, W5tl + 4 * 65536, 2048, HID, HID,
                                         Zs, ZsTh, ZsTl, dinv1, nullptr, nullptr, 0); }
  { dim3 g(4, 32);
    k_mm<0,1,0,3><<<g, 256, 0, stream>>>(A1h, nullptr, ZsTh, ZsTl, 2048, HID, 2048,
                                         xv, nullptr, nullptr, dinv1, Zs, ub1, 1); }

  // ---- up 2 (res=x0, inv1, A0 sparse, Cout=64, no relu) ----
  k_unpool_split<<<4096, 256, 0, stream>>>(x0, xv, inv1, xuh, xul);
  { dim3 g(1, 64);
    k_mm<1,1,0,2><<<g, 256, 0, stream>>>(xuh, xul, W2th, W2tl, 4096, OUT_DIM, HID,
                                         Zs, nullptr, nullptr, dinv0, nullptr, nullptr, 0); }
  k_spmm_ell<64,0,0><<<4096, 256, 0, stream>>>(ell, cnt, Zs, dinv0, ub2, (float*)d_out, nullptr, nullptr);
}

// Round 5
// 298.667 us; speedup vs baseline: 1.8430x; 1.8430x over previous
//
#include <hip/hip_runtime.h>
#include <math.h>

#define NN 4096
#define EE 131072
#define IN_DIM 512
#define HID 256
#define OUT_DIM 64
#define ECAP 128

typedef __attribute__((ext_vector_type(8))) short bf8_t;
typedef __attribute__((ext_vector_type(4))) float f4_t;
typedef __attribute__((ext_vector_type(8))) unsigned short us8_t;

#define GAS __attribute__((address_space(1)))
#define LAS __attribute__((address_space(3)))

// ---------------- bf16 helpers (RNE) ----------------
__device__ __forceinline__ unsigned short f2bf(float v){
  union { float f; unsigned u; } x; x.f = v;
  unsigned r = x.u + 0x7fffu + ((x.u >> 16) & 1u);
  return (unsigned short)(r >> 16);
}
__device__ __forceinline__ float bf2f(unsigned short h){
  union { float f; unsigned u; } x; x.u = ((unsigned)h) << 16;
  return x.f;
}

__device__ __forceinline__ float waveReduceSum(float v){
#pragma unroll
  for (int off = 32; off > 0; off >>= 1) v += __shfl_down(v, off);
  return v;
}

// ---------------- graph build: bitmask + ELL ----------------
__global__ void k_build_bits(const int* __restrict__ ei, unsigned* __restrict__ bits){
  int e = blockIdx.x * blockDim.x + threadIdx.x;
  if (e < EE){
    int r = ei[e], c = ei[EE + e];
    atomicOr(&bits[r * 128 + (c >> 5)], 1u << (c & 31));
  }
}

__global__ __launch_bounds__(128) void k_ell(const unsigned* __restrict__ bits,
                                             int* __restrict__ ell, int* __restrict__ cnt,
                                             float* __restrict__ dinv){
  int r = blockIdx.x, t = threadIdx.x;
  unsigned w = bits[r * 128 + t];
  int c = __popc(w);
  __shared__ int sc[128];
  sc[t] = c; __syncthreads();
  for (int off = 1; off < 128; off <<= 1){
    int a = sc[t], b = (t >= off) ? sc[t - off] : 0;
    __syncthreads(); sc[t] = a + b; __syncthreads();
  }
  int total = sc[127];
  int pos = sc[t] - c;
  int base = r * ECAP;
  while (w){
    int b = __ffs(w) - 1; w &= w - 1;
    if (pos < ECAP) ell[base + pos] = t * 32 + b;
    pos++;
  }
  if (t == 0){
    cnt[r] = (total < ECAP) ? total : ECAP;
    dinv[r] = 1.0f / sqrtf((float)total + 2.0f);
  }
}

// ---------------- fused SpMM (ELL, values==1) + GCN epilogue (+ optional score) ----------------
template<int NCOLS, int RELU, int SC>
__global__ __launch_bounds__(256) void k_spmm_ell(
    const int* __restrict__ ell, const int* __restrict__ cnt,
    const float* __restrict__ Zs, const float* __restrict__ dinv,
    const float* __restrict__ bias, float* __restrict__ out,
    const float* __restrict__ scw, float* __restrict__ score)
{
  int r = blockIdx.x;
  __shared__ int s_idx[ECAP];
  __shared__ int s_n;
  __shared__ float sh[4 * NCOLS];
  __shared__ float sd[4], sq[4];
  if (threadIdx.x == 0) s_n = cnt[r];
  for (int i = threadIdx.x; i < ECAP; i += 256) s_idx[i] = ell[r * ECAP + i];
  __syncthreads();
  int n = s_n; if (n > ECAP) n = ECAP;
  int wv = threadIdx.x >> 6, lane = threadIdx.x & 63;
  if (NCOLS == 256){
    f4_t acc = (f4_t){0.f, 0.f, 0.f, 0.f};
    for (int e = wv; e < n; e += 4){
      const f4_t* row = (const f4_t*)(Zs + (size_t)s_idx[e] * 256);
      acc += row[lane];
    }
    ((f4_t*)(sh + wv * 256))[lane] = acc;
  } else {
    float acc = 0.f;
    for (int e = wv; e < n; e += 4)
      acc += Zs[(size_t)s_idx[e] * 64 + lane];
    sh[wv * 64 + lane] = acc;
  }
  __syncthreads();
  int t = threadIdx.x;
  float o = 0.f;
  if (t < NCOLS){
    float y = sh[t] + sh[NCOLS + t] + sh[2 * NCOLS + t] + sh[3 * NCOLS + t];
    float z = Zs[(size_t)r * NCOLS + t];
    o = dinv[r] * (y + 2.0f * z) + bias[t];
    if (RELU) o = fmaxf(o, 0.f);
    out[(size_t)r * NCOLS + t] = o;
  }
  if (SC){
    float w = scw[t];
    float d = waveReduceSum(o * w);
    float q = waveReduceSum(w * w);
    if (!lane){ sd[wv] = d; sq[wv] = q; }
    __syncthreads();
    if (!t) score[r] = tanhf((sd[0] + sd[1] + sd[2] + sd[3]) / sqrtf(sq[0] + sq[1] + sq[2] + sq[3]));
  }
}

// ---------------- pool-1 squaring (u8 Rb) ----------------
__global__ __launch_bounds__(256) void k_build_Rb(const int* __restrict__ ell, const int* __restrict__ cnt,
                                                  const int* __restrict__ invsel,
                                                  unsigned char* __restrict__ Rb){
  int k = blockIdx.x;
  __shared__ unsigned char row[2048];
  for (int i = threadIdx.x; i < 512; i += 256) ((int*)row)[i] = 0;
  __syncthreads();
  int n = cnt[k];
  for (int e = threadIdx.x; e < n; e += 256){
    int s = invsel[ell[k * ECAP + e]];
    if (s >= 0) row[s] = 1;
  }
  __syncthreads();
  if (threadIdx.x == 0){
    int sk = invsel[k];
    if (sk >= 0) row[sk] += 1;
  }
  __syncthreads();
  *(uint2*)(Rb + (size_t)k * 2048 + threadIdx.x * 8) = *(uint2*)(row + threadIdx.x * 8);
}

__global__ __launch_bounds__(256) void k_sq1(const int* __restrict__ ell, const int* __restrict__ cnt,
                                             const int* __restrict__ perm,
                                             const unsigned char* __restrict__ Rb,
                                             unsigned short* __restrict__ A1h,
                                             float* __restrict__ dinv1){
  int r = blockIdx.x;
  int pr = perm[r];
  __shared__ int s_idx[ECAP];
  __shared__ int s_n;
  __shared__ float sred[4];
  if (threadIdx.x == 0) s_n = cnt[pr];
  for (int i = threadIdx.x; i < ECAP; i += 256) s_idx[i] = ell[pr * ECAP + i];
  __syncthreads();
  int n = s_n; if (n > ECAP) n = ECAP;
  int colb = threadIdx.x * 8;
  uint2 acc = *(const uint2*)(Rb + (size_t)pr * 2048 + colb);
  for (int e = 0; e < n; ++e){
    uint2 v = *(const uint2*)(Rb + (size_t)s_idx[e] * 2048 + colb);
    acc.x += v.x; acc.y += v.y;   // bytewise, no carries (values <=130)
  }
  float fs = 0.f;
  us8_t o;
#pragma unroll
  for (int j = 0; j < 8; ++j){
    unsigned byte = ((j < 4 ? acc.x : acc.y) >> (8 * (j & 3))) & 0xFFu;
    if (colb + j == r) byte = 0;
    float f = (float)byte;
    fs += f;
    o[j] = f2bf(f);
  }
  *(us8_t*)(A1h + (size_t)r * 2048 + colb) = o;
  fs = waveReduceSum(fs);
  int lane = threadIdx.x & 63, wd = threadIdx.x >> 6;
  if (!lane) sred[wd] = fs;
  __syncthreads();
  if (!threadIdx.x)
    dinv1[r] = 1.0f / sqrtf(sred[0] + sred[1] + sred[2] + sred[3] + 2.0f);
}

// ---------------- bf16 transpose (h [+l]) ----------------
template<int TWO>
__global__ __launch_bounds__(256) void k_tr_b(const unsigned short* __restrict__ Sh,
                                              const unsigned short* __restrict__ Sl,
                                              unsigned short* __restrict__ Dh,
                                              unsigned short* __restrict__ Dl, int R, int C){
  __shared__ unsigned short th[32][33];
  __shared__ unsigned short tl[TWO ? 32 : 1][TWO ? 33 : 1];
  int bx = blockIdx.x * 32, by = blockIdx.y * 32;
  int tx = threadIdx.x & 31, ty = threadIdx.x >> 5;
#pragma unroll
  for (int i = 0; i < 4; ++i){
    th[ty + i * 8][tx] = Sh[(size_t)(by + ty + i * 8) * C + bx + tx];
    if (TWO) tl[ty + i * 8][tx] = Sl[(size_t)(by + ty + i * 8) * C + bx + tx];
  }
  __syncthreads();
#pragma unroll
  for (int i = 0; i < 4; ++i){
    size_t o = (size_t)(bx + ty + i * 8) * R + by + tx;
    Dh[o] = th[tx][ty + i * 8];
    if (TWO) Dl[o] = tl[tx][ty + i * 8];
  }
}

// ---------------- split-K MFMA GEMM: partials only ----------------
// P[z][M][N] += slice-z of (Ah[+Al]) @ (Bh[+Bl]); A [M][K] bf16 row-major, B as Bt [N][K].
// Staging: global_load_lds(16B) double-buffered; LDS XOR-swizzle via pre-swizzled source.
template<int HAS_AL, int HAS_BL, int HAS_LL>
__global__ __launch_bounds__(256) void k_mm(
    const unsigned short* __restrict__ Ah, const unsigned short* __restrict__ Al,
    const unsigned short* __restrict__ Bh, const unsigned short* __restrict__ Bl,
    int M, int N, int K, int KS, float* __restrict__ P)
{
  constexpr int NARR = 2 + HAS_AL + HAS_BL;
  constexpr int BUF = NARR * 8192;
  __shared__ int4 ldsq[NARR * 512 * 2];
  char* ldsc = (char*)ldsq;

  const int tid = threadIdx.x, lane = tid & 63, wid = tid >> 6;
  const int wm = wid >> 1, wn = wid & 1;
  const int bm = blockIdx.y << 6, bn = blockIdx.x << 6;
  const int z = blockIdx.z;
  const int l15 = lane & 15, l4 = lane >> 4;

  f4_t acc[2][2];
#pragma unroll
  for (int i = 0; i < 2; ++i)
#pragma unroll
    for (int j = 0; j < 2; ++j) acc[i][j] = (f4_t){0.f, 0.f, 0.f, 0.f};

  const size_t rb = (size_t)K * 2;
  const size_t kz = (size_t)z * KS * 2;
  const char* pAh = (const char*)Ah + (size_t)bm * rb;
  const char* pAl = HAS_AL ? (const char*)Al + (size_t)bm * rb : nullptr;
  const char* pBh = (const char*)Bh + (size_t)bn * rb;
  const char* pBl = HAS_BL ? (const char*)Bl + (size_t)bn * rb : nullptr;

  auto stage = [&](int t, int b2){
    char* ldsb = ldsc + b2 * BUF;
    const size_t kb = kz + (size_t)t * 128;
#pragma unroll
    for (int it = 0; it < 2; ++it){
      const int idx = tid + (it << 8);
      const int row = idx >> 3;
      const int kc = ((idx & 7) << 4) ^ ((row & 7) << 4);  // pre-swizzled source col
      const size_t go = (size_t)row * rb + kb + kc;
      const int lo = idx * 16;                             // linear LDS dest
      __builtin_amdgcn_global_load_lds((const GAS void*)(pAh + go), (LAS void*)(ldsb + lo), 16, 0, 0);
      __builtin_amdgcn_global_load_lds((const GAS void*)(pBh + go), (LAS void*)(ldsb + 8192 + lo), 16, 0, 0);
      if (HAS_AL)
        __builtin_amdgcn_global_load_lds((const GAS void*)(pAl + go), (LAS void*)(ldsb + 16384 + lo), 16, 0, 0);
      if (HAS_BL)
        __builtin_amdgcn_global_load_lds((const GAS void*)(pBl + go), (LAS void*)(ldsb + (2 + HAS_AL) * 8192 + lo), 16, 0, 0);
    }
  };

  const int T = KS >> 6;
  stage(0, 0);
  int b = 0;
  for (int t = 0; t < T; ++t){
    if (t + 1 < T){
      stage(t + 1, b ^ 1);
      if constexpr (NARR == 2) asm volatile("s_waitcnt vmcnt(4)" ::: "memory");
      else if constexpr (NARR == 3) asm volatile("s_waitcnt vmcnt(6)" ::: "memory");
      else asm volatile("s_waitcnt vmcnt(8)" ::: "memory");
    } else {
      asm volatile("s_waitcnt vmcnt(0)" ::: "memory");
    }
    __syncthreads();
    const char* ldsb = ldsc + b * BUF;
#pragma unroll
    for (int ks = 0; ks < 2; ++ks){
      bf8_t aH[2], aL[2], bH[2], bL[2];
#pragma unroll
      for (int f = 0; f < 2; ++f){
        int ar = wm * 32 + f * 16 + l15;
        int aoff = ar * 128 + (((ks * 64) + (l4 << 4)) ^ ((ar & 7) << 4));
        aH[f] = *(const bf8_t*)(ldsb + aoff);
        if (HAS_AL) aL[f] = *(const bf8_t*)(ldsb + 16384 + aoff);
        int br = wn * 32 + f * 16 + l15;
        int boff = br * 128 + (((ks * 64) + (l4 << 4)) ^ ((br & 7) << 4));
        bH[f] = *(const bf8_t*)(ldsb + 8192 + boff);
        if (HAS_BL) bL[f] = *(const bf8_t*)(ldsb + (2 + HAS_AL) * 8192 + boff);
      }
#pragma unroll
      for (int i = 0; i < 2; ++i)
#pragma unroll
        for (int j = 0; j < 2; ++j){
          acc[i][j] = __builtin_amdgcn_mfma_f32_16x16x32_bf16(aH[i], bH[j], acc[i][j], 0, 0, 0);
          if (HAS_BL) acc[i][j] = __builtin_amdgcn_mfma_f32_16x16x32_bf16(aH[i], bL[j], acc[i][j], 0, 0, 0);
          if (HAS_AL) acc[i][j] = __builtin_amdgcn_mfma_f32_16x16x32_bf16(aL[i], bH[j], acc[i][j], 0, 0, 0);
          if (HAS_LL) acc[i][j] = __builtin_amdgcn_mfma_f32_16x16x32_bf16(aL[i], bL[j], acc[i][j], 0, 0, 0);
        }
    }
    __syncthreads();
    b ^= 1;
  }

  float* Pz = P + (size_t)z * M * N;
#pragma unroll
  for (int i = 0; i < 2; ++i)
#pragma unroll
    for (int j = 0; j < 2; ++j)
#pragma unroll
      for (int r = 0; r < 4; ++r){
        int grow = bm + wm * 32 + i * 16 + l4 * 4 + r;
        int gcol = bn + wn * 32 + j * 16 + l15;
        Pz[(size_t)grow * N + gcol] = acc[i][j][r];
      }
}

// ---------------- split-K reduce + fused epilogues (one block per row) ----------------
// EPI 0: Of = dinv[row]*s
// EPI 1: sv = dinv[row]*s; Of = sv; Oh/Ol[c*M+row] = split(sv)   (transposed split)
// EPI 2: Of = relu?(dinv[row]*(s + 2*Zs) + bias)
// EPI 3: v = (c==row) ? 0 : s; Oh/Ol = split(v); dout[row] = 1/sqrt(rowsum+2)
template<int EPI>
__global__ __launch_bounds__(256) void k_red(const float* __restrict__ P, int Z, int M, int NC,
                      const float* __restrict__ dinv, const float* __restrict__ Zs,
                      const float* __restrict__ bias,
                      float* __restrict__ Of, unsigned short* __restrict__ Oh,
                      unsigned short* __restrict__ Ol, float* __restrict__ dout, int relu){
  int row = blockIdx.x;
  float rsum = 0.f;
  for (int c = threadIdx.x; c < NC; c += 256){
    size_t o = (size_t)row * NC + c;
    float s = P[o];
    for (int zz = 1; zz < Z; ++zz) s += P[(size_t)zz * M * NC + o];
    if (EPI == 0){
      Of[o] = dinv[row] * s;
    } else if (EPI == 1){
      float sv = dinv[row] * s;
      Of[o] = sv;
      unsigned short h = f2bf(sv);
      size_t ot = (size_t)c * M + row;
      Oh[ot] = h; Ol[ot] = f2bf(sv - bf2f(h));
    } else if (EPI == 2){
      float out = dinv[row] * (s + 2.0f * Zs[o]) + bias[c];
      if (relu) out = fmaxf(out, 0.f);
      Of[o] = out;
    } else {
      float v = (c == row) ? 0.f : s;
      unsigned short h = f2bf(v);
      Oh[o] = h; Ol[o] = f2bf(v - bf2f(h));
      rsum += v;
    }
  }
  if (EPI == 3){
    rsum = waveReduceSum(rsum);
    __shared__ float sr[4];
    int lane = threadIdx.x & 63, wd = threadIdx.x >> 6;
    if (!lane) sr[wd] = rsum;
    __syncthreads();
    if (!threadIdx.x) dout[row] = 1.0f / sqrtf(sr[0] + sr[1] + sr[2] + sr[3] + 2.0f);
  }
}

// ---------------- elementwise helpers ----------------
__global__ void k_split(const float* __restrict__ X, unsigned short* __restrict__ H,
                        unsigned short* __restrict__ L, int n){
  int i = blockIdx.x * 256 + threadIdx.x;
  if (i < n){
    float v = X[i];
    unsigned short h = f2bf(v);
    H[i] = h; L[i] = f2bf(v - bf2f(h));
  }
}

__global__ __launch_bounds__(256) void k_tsplit(const float* __restrict__ X, int R, int C,
                                                unsigned short* __restrict__ Th,
                                                unsigned short* __restrict__ Tl){
  __shared__ float t[32][33];
  int bx = blockIdx.x * 32, by = blockIdx.y * 32;
  int tx = threadIdx.x & 31, ty = threadIdx.x >> 5;
#pragma unroll
  for (int i = 0; i < 4; ++i)
    t[ty + i * 8][tx] = X[(size_t)(by + ty + i * 8) * C + bx + tx];
  __syncthreads();
#pragma unroll
  for (int i = 0; i < 4; ++i){
    float v = t[tx][ty + i * 8];
    unsigned short h = f2bf(v);
    size_t o = (size_t)(bx + ty + i * 8) * R + by + tx;
    Th[o] = h; Tl[o] = f2bf(v - bf2f(h));
  }
}

__global__ __launch_bounds__(256) void k_tsplit5(const float* __restrict__ w0, const float* __restrict__ w1,
                                                 const float* __restrict__ w2, const float* __restrict__ w3,
                                                 const float* __restrict__ w4,
                                                 unsigned short* __restrict__ Th, unsigned short* __restrict__ Tl){
  const float* X = (blockIdx.z == 0) ? w0 : (blockIdx.z == 1) ? w1 : (blockIdx.z == 2) ? w2 :
                   (blockIdx.z == 3) ? w3 : w4;
  unsigned short* th = Th + (size_t)blockIdx.z * 65536;
  unsigned short* tl = Tl + (size_t)blockIdx.z * 65536;
  __shared__ float t[32][33];
  int bx = blockIdx.x * 32, by = blockIdx.y * 32;
  int tx = threadIdx.x & 31, ty = threadIdx.x >> 5;
#pragma unroll
  for (int i = 0; i < 4; ++i)
    t[ty + i * 8][tx] = X[(size_t)(by + ty + i * 8) * 256 + bx + tx];
  __syncthreads();
#pragma unroll
  for (int i = 0; i < 4; ++i){
    float v = t[tx][ty + i * 8];
    unsigned short h = f2bf(v);
    size_t o = (size_t)(bx + ty + i * 8) * 256 + by + tx;
    th[o] = h; tl[o] = f2bf(v - bf2f(h));
  }
}

__global__ void k_score(const float* __restrict__ x, const float* __restrict__ w,
                        float* __restrict__ score){
  int row = blockIdx.x;
  float wv = w[threadIdx.x];
  float xv = x[(size_t)row * HID + threadIdx.x];
  float d = waveReduceSum(xv * wv);
  float q = waveReduceSum(wv * wv);
  __shared__ float sd[4], sq[4];
  int lane = threadIdx.x & 63, wd = threadIdx.x >> 6;
  if (!lane){ sd[wd] = d; sq[wd] = q; }
  __syncthreads();
  if (!threadIdx.x)
    score[row] = tanhf((sd[0] + sd[1] + sd[2] + sd[3]) / sqrtf(sq[0] + sq[1] + sq[2] + sq[3]));
}

__global__ void k_topk(const float* __restrict__ score, int n, int k,
                       int* __restrict__ perm, int* __restrict__ inv){
  int i = blockIdx.x; float si = score[i];
  int cnt = 0;
  for (int j = threadIdx.x; j < n; j += 256){
    float sj = score[j];
    if (sj > si || (sj == si && j < i)) cnt++;
  }
#pragma unroll
  for (int off = 32; off > 0; off >>= 1) cnt += __shfl_down(cnt, off);
  __shared__ int sh[4];
  int lane = threadIdx.x & 63, wid = threadIdx.x >> 6;
  if (lane == 0) sh[wid] = cnt;
  __syncthreads();
  if (threadIdx.x == 0){
    int rank = sh[0] + sh[1] + sh[2] + sh[3];
    if (rank < k){ perm[rank] = i; inv[i] = rank; }
    else inv[i] = -1;
  }
}

__global__ void k_pool_x2(const float* __restrict__ x, const float* __restrict__ score,
                          const int* __restrict__ perm,
                          unsigned short* __restrict__ xh, unsigned short* __restrict__ xl, int C){
  int r = blockIdx.x; int pr = perm[r]; float s = score[pr];
  for (int c = threadIdx.x; c < C; c += 256){
    float v = x[(size_t)pr * C + c] * s;
    unsigned short h = f2bf(v);
    xh[(size_t)r * C + c] = h;
    xl[(size_t)r * C + c] = f2bf(v - bf2f(h));
  }
}

template<int SRCL, int OUTL>
__global__ void k_grow_b(const unsigned short* __restrict__ Sh, const unsigned short* __restrict__ Sl,
                         const int* __restrict__ perm,
                         unsigned short* __restrict__ Dh, unsigned short* __restrict__ Dl, int n){
  int r = blockIdx.x, pr = perm[r];
  for (int c = threadIdx.x; c < n; c += 256){
    float v = bf2f(Sh[(size_t)pr * n + c]);
    if (SRCL) v += bf2f(Sl[(size_t)pr * n + c]);
    if (pr == c) v += 1.f;
    unsigned short h = f2bf(v);
    Dh[(size_t)r * n + c] = h;
    if (OUTL) Dl[(size_t)r * n + c] = f2bf(v - bf2f(h));
  }
}

__global__ void k_unpool_split(const float* __restrict__ res, const float* __restrict__ xs,
                               const int* __restrict__ inv,
                               unsigned short* __restrict__ xh, unsigned short* __restrict__ xl){
  int r = blockIdx.x; int ir = inv[r];
  int c = threadIdx.x;
  float v = res[(size_t)r * HID + c];
  if (ir >= 0) v += xs[(size_t)ir * HID + c];
  unsigned short h = f2bf(v);
  xh[(size_t)r * HID + c] = h;
  xl[(size_t)r * HID + c] = f2bf(v - bf2f(h));
}

// ---------------- host orchestration ----------------
extern "C" void kernel_launch(void* const* d_in, const int* in_sizes, int n_in,
                              void* d_out, int out_size, void* d_ws, size_t ws_size,
                              hipStream_t stream){
  (void)in_sizes; (void)n_in; (void)out_size;
  const float* x_in = (const float*)d_in[0];
  const int*   ei   = (const int*)d_in[1];
  const float* dW0 = (const float*)d_in[2];
  const float* dW1 = (const float*)d_in[3];
  const float* dW2 = (const float*)d_in[4];
  const float* dW3 = (const float*)d_in[5];
  const float* db0 = (const float*)d_in[6];
  const float* db1 = (const float*)d_in[7];
  const float* db2 = (const float*)d_in[8];
  const float* db3 = (const float*)d_in[9];
  const float* pw0 = (const float*)d_in[10];
  const float* pw1 = (const float*)d_in[11];
  const float* pw2 = (const float*)d_in[12];
  const float* uW0 = (const float*)d_in[13];
  const float* uW1 = (const float*)d_in[14];
  const float* uW2 = (const float*)d_in[15];
  const float* ub0 = (const float*)d_in[16];
  const float* ub1 = (const float*)d_in[17];
  const float* ub2 = (const float*)d_in[18];

  char* p = (char*)d_ws;
  auto alloc = [&](size_t nbytes) -> void* {
    void* q = (void*)p; p += (nbytes + 255) & ~(size_t)255; return q;
  };
  unsigned* bits = (unsigned*)alloc((size_t)4096 * 128 * 4);
  int* ell = (int*)alloc((size_t)4096 * ECAP * 4);
  int* cnt = (int*)alloc(4096 * 4);
  int* inv1 = (int*)alloc(4096 * 4);
  int* inv2 = (int*)alloc(2048 * 4);
  int* inv3 = (int*)alloc(1024 * 4);
  unsigned char* Rb = (unsigned char*)alloc((size_t)4096 * 2048);
  float* Pp = (float*)alloc((size_t)8 * 1024 * 1024);   // split-K partials (max 8 MB)
  unsigned short* A1h = (unsigned short*)alloc((size_t)2048 * 2048 * 2);
  unsigned short* A1T = (unsigned short*)alloc((size_t)2048 * 2048 * 2);
  unsigned short* A2h = (unsigned short*)alloc((size_t)1024 * 1024 * 2);
  unsigned short* A2l = (unsigned short*)alloc((size_t)1024 * 1024 * 2);
  unsigned short* A2Th = (unsigned short*)alloc((size_t)1024 * 1024 * 2);
  unsigned short* A2Tl = (unsigned short*)alloc((size_t)1024 * 1024 * 2);
  unsigned short* A3h = (unsigned short*)alloc((size_t)512 * 512 * 2);
  unsigned short* A3l = (unsigned short*)alloc((size_t)512 * 512 * 2);
  unsigned short* Lb2h = (unsigned short*)alloc((size_t)1024 * 2048 * 2);
  unsigned short* Rt2h = (unsigned short*)alloc((size_t)1024 * 2048 * 2);
  unsigned short* Lb3h = (unsigned short*)alloc((size_t)512 * 1024 * 2);
  unsigned short* Lb3l = (unsigned short*)alloc((size_t)512 * 1024 * 2);
  unsigned short* Rt3h = (unsigned short*)alloc((size_t)512 * 1024 * 2);
  unsigned short* Rt3l = (unsigned short*)alloc((size_t)512 * 1024 * 2);
  unsigned short* xinh = (unsigned short*)alloc((size_t)4096 * 512 * 2);
  unsigned short* xinl = (unsigned short*)alloc((size_t)4096 * 512 * 2);
  float* x0 = (float*)alloc((size_t)4096 * HID * 4);
  float* x1 = (float*)alloc((size_t)2048 * HID * 4);
  float* x2 = (float*)alloc((size_t)1024 * HID * 4);
  float* xv = (float*)alloc((size_t)2048 * HID * 4);
  unsigned short* xuh = (unsigned short*)alloc((size_t)4096 * HID * 2);
  unsigned short* xul = (unsigned short*)alloc((size_t)4096 * HID * 2);
  unsigned short* xph = (unsigned short*)alloc((size_t)2048 * HID * 2);
  unsigned short* xpl = (unsigned short*)alloc((size_t)2048 * HID * 2);
  unsigned short* W0th = (unsigned short*)alloc((size_t)256 * 512 * 2);
  unsigned short* W0tl = (unsigned short*)alloc((size_t)256 * 512 * 2);
  unsigned short* W5th = (unsigned short*)alloc((size_t)5 * 256 * 256 * 2);
  unsigned short* W5tl = (unsigned short*)alloc((size_t)5 * 256 * 256 * 2);
  unsigned short* W2th = (unsigned short*)alloc((size_t)64 * 256 * 2);
  unsigned short* W2tl = (unsigned short*)alloc((size_t)64 * 256 * 2);
  float* Zs  = (float*)alloc((size_t)4096 * HID * 4);
  unsigned short* ZsTh = (unsigned short*)alloc((size_t)256 * 2048 * 2);
  unsigned short* ZsTl = (unsigned short*)alloc((size_t)256 * 2048 * 2);
  float* dinv0 = (float*)alloc(4096 * 4);
  float* dinv1 = (float*)alloc(2048 * 4);
  float* dinv2 = (float*)alloc(1024 * 4);
  float* dinv3 = (float*)alloc(512 * 4);
  float* score = (float*)alloc(4096 * 4);
  int* perm1 = (int*)alloc(2048 * 4);
  int* perm2 = (int*)alloc(1024 * 4);
  int* perm3 = (int*)alloc(512 * 4);
  if ((size_t)(p - (char*)d_ws) > ws_size) return;

  // ---- weight prep ----
  { dim3 g(8, 16); k_tsplit<<<g, 256, 0, stream>>>(dW0, IN_DIM, HID, W0th, W0tl); }
  { dim3 g(8, 8, 5); k_tsplit5<<<g, 256, 0, stream>>>(dW1, dW2, dW3, uW0, uW1, W5th, W5tl); }
  { dim3 g(2, 8); k_tsplit<<<g, 256, 0, stream>>>(uW2, HID, OUT_DIM, W2th, W2tl); }

  // ---- graph build ----
  hipMemsetAsync(bits, 0, (size_t)4096 * 128 * 4, stream);
  k_build_bits<<<EE / 256, 256, 0, stream>>>(ei, bits);
  k_ell<<<4096, 128, 0, stream>>>(bits, ell, cnt, dinv0);

  // ---- conv0 ----
  k_split<<<(4096 * 512 + 255) / 256, 256, 0, stream>>>(x_in, xinh, xinl, 4096 * 512);
  { dim3 g(4, 64, 2);
    k_mm<1,1,0><<<g, 256, 0, stream>>>(xinh, xinl, W0th, W0tl, 4096, HID, IN_DIM, 256, Pp); }
  k_red<0><<<4096, 256, 0, stream>>>(Pp, 2, 4096, 256, dinv0, nullptr, nullptr,
                                     Zs, nullptr, nullptr, nullptr, 0);
  k_spmm_ell<256,1,1><<<4096, 256, 0, stream>>>(ell, cnt, Zs, dinv0, db0, x0, pw0, score);

  // ---- pool 1 (4096 -> 2048) ----
  k_topk<<<4096, 256, 0, stream>>>(score, 4096, 2048, perm1, inv1);
  k_pool_x2<<<2048, 256, 0, stream>>>(x0, score, perm1, xph, xpl, HID);
  k_build_Rb<<<4096, 256, 0, stream>>>(ell, cnt, inv1, Rb);
  k_sq1<<<2048, 256, 0, stream>>>(ell, cnt, perm1, Rb, A1h, dinv1);
  // conv1
  { dim3 g(4, 32, 2);
    k_mm<1,1,0><<<g, 256, 0, stream>>>(xph, xpl, W5th, W5tl, 2048, HID, HID, 128, Pp); }
  k_red<1><<<2048, 256, 0, stream>>>(Pp, 2, 2048, 256, dinv1, nullptr, nullptr,
                                     Zs, ZsTh, ZsTl, nullptr, 0);
  { dim3 g(4, 32, 4);
    k_mm<0,1,0><<<g, 256, 0, stream>>>(A1h, nullptr, ZsTh, ZsTl, 2048, HID, 2048, 512, Pp); }
  k_red<2><<<2048, 256, 0, stream>>>(Pp, 4, 2048, 256, dinv1, Zs, db1,
                                     x1, nullptr, nullptr, nullptr, 1);

  // ---- pool 2 (2048 -> 1024) ----
  k_score<<<2048, 256, 0, stream>>>(x1, pw1, score);
  k_topk<<<2048, 256, 0, stream>>>(score, 2048, 1024, perm2, inv2);
  { dim3 g(64, 64); k_tr_b<0><<<g, 256, 0, stream>>>(A1h, nullptr, A1T, nullptr, 2048, 2048); }
  k_grow_b<0,0><<<1024, 256, 0, stream>>>(A1h, nullptr, perm2, Lb2h, nullptr, 2048);
  k_grow_b<0,0><<<1024, 256, 0, stream>>>(A1T, nullptr, perm2, Rt2h, nullptr, 2048);
  { dim3 g(16, 16, 2);
    k_mm<0,0,0><<<g, 256, 0, stream>>>(Lb2h, nullptr, Rt2h, nullptr, 1024, 1024, 2048, 1024, Pp); }
  k_red<3><<<1024, 256, 0, stream>>>(Pp, 2, 1024, 1024, nullptr, nullptr, nullptr,
                                     nullptr, A2h, A2l, dinv2, 0);
  k_pool_x2<<<1024, 256, 0, stream>>>(x1, score, perm2, xph, xpl, HID);
  // conv2
  { dim3 g(4, 16, 4);
    k_mm<1,1,0><<<g, 256, 0, stream>>>(xph, xpl, W5th + 65536, W5tl + 65536, 1024, HID, HID, 64, Pp); }
  k_red<1><<<1024, 256, 0, stream>>>(Pp, 4, 1024, 256, dinv2, nullptr, nullptr,
                                     Zs, ZsTh, ZsTl, nullptr, 0);
  { dim3 g(4, 16, 4);
    k_mm<1,1,0><<<g, 256, 0, stream>>>(A2h, A2l, ZsTh, ZsTl, 1024, HID, 1024, 256, Pp); }
  k_red<2><<<1024, 256, 0, stream>>>(Pp, 4, 1024, 256, dinv2, Zs, db2,
                                     x2, nullptr, nullptr, nullptr, 1);

  // ---- pool 3 (1024 -> 512) ----
  k_score<<<1024, 256, 0, stream>>>(x2, pw2, score);
  k_topk<<<1024, 256, 0, stream>>>(score, 1024, 512, perm3, inv3);
  { dim3 g(32, 32); k_tr_b<1><<<g, 256, 0, stream>>>(A2h, A2l, A2Th, A2Tl, 1024, 1024); }
  k_grow_b<1,1><<<512, 256, 0, stream>>>(A2h, A2l, perm3, Lb3h, Lb3l, 1024);
  k_grow_b<1,1><<<512, 256, 0, stream>>>(A2Th, A2Tl, perm3, Rt3h, Rt3l, 1024);
  { dim3 g(8, 8, 4);
    k_mm<1,1,1><<<g, 256, 0, stream>>>(Lb3h, Lb3l, Rt3h, Rt3l, 512, 512, 1024, 256, Pp); }
  k_red<3><<<512, 256, 0, stream>>>(Pp, 4, 512, 512, nullptr, nullptr, nullptr,
                                    nullptr, A3h, A3l, dinv3, 0);
  k_pool_x2<<<512, 256, 0, stream>>>(x2, score, perm3, xph, xpl, HID);
  // conv3
  { dim3 g(4, 8, 4);
    k_mm<1,1,0><<<g, 256, 0, stream>>>(xph, xpl, W5th + 2 * 65536, W5tl + 2 * 65536, 512, HID, HID, 64, Pp); }
  k_red<1><<<512, 256, 0, stream>>>(Pp, 4, 512, 256, dinv3, nullptr, nullptr,
                                    Zs, ZsTh, ZsTl, nullptr, 0);
  { dim3 g(4, 8, 4);
    k_mm<1,1,0><<<g, 256, 0, stream>>>(A3h, A3l, ZsTh, ZsTl, 512, HID, 512, 128, Pp); }
  k_red<2><<<512, 256, 0, stream>>>(Pp, 4, 512, 256, dinv3, Zs, db3,
                                    xv, nullptr, nullptr, nullptr, 1);   // xv = x3

  // ---- up 0 (res=x2, inv3, A2) ----
  k_unpool_split<<<1024, 256, 0, stream>>>(x2, xv, inv3, xuh, xul);
  { dim3 g(4, 16, 4);
    k_mm<1,1,0><<<g, 256, 0, stream>>>(xuh, xul, W5th + 3 * 65536, W5tl + 3 * 65536, 1024, HID, HID, 64, Pp); }
  k_red<1><<<1024, 256, 0, stream>>>(Pp, 4, 1024, 256, dinv2, nullptr, nullptr,
                                     Zs, ZsTh, ZsTl, nullptr, 0);
  { dim3 g(4, 16, 4);
    k_mm<1,1,0><<<g, 256, 0, stream>>>(A2h, A2l, ZsTh, ZsTl, 1024, HID, 1024, 256, Pp); }
  k_red<2><<<1024, 256, 0, stream>>>(Pp, 4, 1024, 256, dinv2, Zs, ub0,
                                     xv, nullptr, nullptr, nullptr, 1);

  // ---- up 1 (res=x1, inv2, A1) ----
  k_unpool_split<<<2048, 256, 0, stream>>>(x1, xv, inv2, xuh, xul);
  { dim3 g(4, 32, 2);
    k_mm<1,1,0><<<g, 256, 0, stream>>>(xuh, xul, W5th + 4 * 65536, W5tl + 4 * 65536, 2048, HID, HID, 128, Pp); }
  k_red<1><<<2048, 256, 0, stream>>>(Pp, 2, 2048, 256, dinv1, nullptr, nullptr,
                                     Zs, ZsTh, ZsTl, nullptr, 0);
  { dim3 g(4, 32, 4);
    k_mm<0,1,0><<<g, 256, 0, stream>>>(A1h, nullptr, ZsTh, ZsTl, 2048, HID, 2048, 512, Pp); }
  k_red<2><<<2048, 256, 0, stream>>>(Pp, 4, 2048, 256, dinv1, Zs, ub1,
                                     xv, nullptr, nullptr, nullptr, 1);

  // ---- up 2 (res=x0, inv1, A0 sparse, Cout=64, no relu) ----
  k_unpool_split<<<4096, 256, 0, stream>>>(x0, xv, inv1, xuh, xul);
  { dim3 g(1, 64, 4);
    k_mm<1,1,0><<<g, 256, 0, stream>>>(xuh, xul, W2th, W2tl, 4096, OUT_DIM, HID, 64, Pp); }
  k_red<0><<<4096, 256, 0, stream>>>(Pp, 4, 4096, 64, dinv0, nullptr, nullptr,
                                     Zs, nullptr, nullptr, nullptr, 0);
  k_spmm_ell<64,0,0><<<4096, 256, 0, stream>>>(ell, cnt, Zs, dinv0, ub2, (float*)d_out, nullptr, nullptr);
}